// Round 1
// baseline (216.878 us; speedup 1.0000x reference)
//
#include <hip/hip_runtime.h>
#include <hip/hip_bf16.h>
#include <math.h>

typedef short short8 __attribute__((ext_vector_type(8)));
typedef __bf16 bf16x8 __attribute__((ext_vector_type(8)));
typedef float f32x4 __attribute__((ext_vector_type(4)));

#define SEQ 4096
#define QK_SCALE 0.18033688011112042f  /* (1/8) * log2(e) */

__device__ __forceinline__ short f2bf(float f) {
    __bf16 h = (__bf16)f;
    return __builtin_bit_cast(short, h);
}

__device__ __forceinline__ f32x4 mfma16(short8 a, short8 b, f32x4 c) {
    return __builtin_amdgcn_mfma_f32_16x16x32_bf16(
        __builtin_bit_cast(bf16x8, a), __builtin_bit_cast(bf16x8, b), c, 0, 0, 0);
}

// ---- kernel 1: W fp32 -> bf16 (W_Q pre-scaled by 1/8*log2e) ----
__global__ __launch_bounds__(256) void wconv_kernel(
    const float* __restrict__ wq, const float* __restrict__ wk,
    const float* __restrict__ wv, short* __restrict__ out) {
  int i = blockIdx.x * 256 + threadIdx.x;
  int arr = i >> 15;
  int idx = i & 32767;
  float v;
  if (arr == 0)      v = wq[idx] * QK_SCALE;
  else if (arr == 1) v = wk[idx];
  else               v = wv[idx];
  out[i] = f2bf(v);
}

// ---- kernel 2: QKV projection. Q,K row-major bf16 [B*S][64]; V transposed
// Vt[b][k][s] bf16. 64 rows/block, 4 waves, each wave 16 rows. ----
__global__ __launch_bounds__(256) void proj_kernel(
    const float* __restrict__ x, const short* __restrict__ wbf,
    short* __restrict__ Qs, short* __restrict__ Ks, short* __restrict__ Vt) {
  __shared__ short vt[4][16][68];  // padded: stride 68 shorts breaks 4-group bank aliasing
  const int wave = threadIdx.x >> 6, lane = threadIdx.x & 63;
  const int g = lane >> 4, r = lane & 15;
  const int rbase = blockIdx.x * 64 + wave * 16;
  const short* wq = wbf;
  const short* wk = wbf + 32768;
  const short* wv = wbf + 65536;

  f32x4 aq[4], ak[4], av[4];
#pragma unroll
  for (int nb = 0; nb < 4; ++nb) { aq[nb] = (f32x4)0.f; ak[nb] = (f32x4)0.f; av[nb] = (f32x4)0.f; }

  const float* xp = x + (size_t)(rbase + r) * 512;
#pragma unroll 4
  for (int k0 = 0; k0 < 512; k0 += 32) {
    const int kb = k0 + g * 8;
    f32x4 f0 = *(const f32x4*)(xp + kb);
    f32x4 f1 = *(const f32x4*)(xp + kb + 4);
    short8 a;
    a[0] = f2bf(f0[0]); a[1] = f2bf(f0[1]); a[2] = f2bf(f0[2]); a[3] = f2bf(f0[3]);
    a[4] = f2bf(f1[0]); a[5] = f2bf(f1[1]); a[6] = f2bf(f1[2]); a[7] = f2bf(f1[3]);
#pragma unroll
    for (int nb = 0; nb < 4; ++nb) {
      const int wrow = (nb * 16 + r) * 512 + kb;
      short8 bq = *(const short8*)(wq + wrow);
      short8 bk = *(const short8*)(wk + wrow);
      short8 bv = *(const short8*)(wv + wrow);
      aq[nb] = mfma16(a, bq, aq[nb]);
      ak[nb] = mfma16(a, bk, ak[nb]);
      av[nb] = mfma16(a, bv, av[nb]);
    }
  }

  // store Q, K (scattered 2B, 32B-contiguous per 16-lane group); V -> LDS
#pragma unroll
  for (int nb = 0; nb < 4; ++nb) {
#pragma unroll
    for (int reg = 0; reg < 4; ++reg) {
      const size_t row = (size_t)(rbase + g * 4 + reg);
      Qs[row * 64 + nb * 16 + r] = f2bf(aq[nb][reg]);
      Ks[row * 64 + nb * 16 + r] = f2bf(ak[nb][reg]);
      vt[wave][g * 4 + reg][nb * 16 + r] = f2bf(av[nb][reg]);
    }
  }
  __syncthreads();
  // transpose store: lane = dk column, 16 seq entries contiguous
  const int b = rbase >> 12, sb = rbase & 4095;
  short* vrow = Vt + ((size_t)(b * 64 + lane)) * SEQ + sb;
  short8 v0, v1;
#pragma unroll
  for (int j = 0; j < 8; ++j) v0[j] = vt[wave][j][lane];
#pragma unroll
  for (int j = 0; j < 8; ++j) v1[j] = vt[wave][j + 8][lane];
  *(short8*)(vrow) = v0;
  *(short8*)(vrow + 8) = v1;
}

// ---- kernel 3: flash attention, causal. 1 wave per block = 16 q rows. ----
__global__ __launch_bounds__(64) void attn_kernel(
    const short* __restrict__ Qs, const short* __restrict__ Ks,
    const short* __restrict__ Vt, float* __restrict__ out) {
  __shared__ short pt[16][72];  // P tile, padded row stride (144 B)
  const int blk = blockIdx.x;
  const int b = blk & 3;
  const int t = 255 - (blk >> 2);  // longest tiles dispatch first
  const int lane = threadIdx.x;
  const int g = lane >> 4, r = lane & 15;
  const int qbase = t * 16;
  const short* Qb = Qs + (size_t)b * (SEQ * 64);
  const short* Kb = Ks + (size_t)b * (SEQ * 64);
  const short* Vb = Vt + (size_t)b * (64 * SEQ);

  const short8 qf0 = *(const short8*)(Qb + (qbase + r) * 64 + g * 8);
  const short8 qf1 = *(const short8*)(Qb + (qbase + r) * 64 + 32 + g * 8);

  f32x4 o[4];
  float m[4], l[4];
#pragma unroll
  for (int i = 0; i < 4; ++i) { o[i] = (f32x4)0.f; m[i] = -1e30f; l[i] = 0.f; }

  const int smax = qbase + 15;
  for (int s0 = 0; s0 <= smax; s0 += 64) {
    // ---- S = Q K^T (pre-scaled to log2 domain) ----
    f32x4 sc[4];
#pragma unroll
    for (int nc = 0; nc < 4; ++nc) {
      sc[nc] = (f32x4)0.f;
      const short* kp = Kb + (size_t)(s0 + nc * 16 + r) * 64 + g * 8;
      short8 kf0 = *(const short8*)(kp);
      short8 kf1 = *(const short8*)(kp + 32);
      sc[nc] = mfma16(qf0, kf0, sc[nc]);
      sc[nc] = mfma16(qf1, kf1, sc[nc]);
    }
    // ---- causal mask (only near diagonal) ----
    if (s0 + 63 > qbase) {
#pragma unroll
      for (int nc = 0; nc < 4; ++nc) {
        const int s = s0 + nc * 16 + r;
#pragma unroll
        for (int reg = 0; reg < 4; ++reg) {
          const int q = qbase + g * 4 + reg;
          if (s > q) sc[nc][reg] = -1e30f;
        }
      }
    }
    // ---- online softmax (base-2) ----
    float mb[4];
#pragma unroll
    for (int reg = 0; reg < 4; ++reg)
      mb[reg] = fmaxf(fmaxf(sc[0][reg], sc[1][reg]), fmaxf(sc[2][reg], sc[3][reg]));
#pragma unroll
    for (int xm = 1; xm <= 8; xm <<= 1) {
#pragma unroll
      for (int reg = 0; reg < 4; ++reg)
        mb[reg] = fmaxf(mb[reg], __shfl_xor(mb[reg], xm));
    }
    float fac[4], rs[4];
#pragma unroll
    for (int reg = 0; reg < 4; ++reg) {
      const float mn = fmaxf(m[reg], mb[reg]);
      fac[reg] = exp2f(m[reg] - mn);
      m[reg] = mn;
      rs[reg] = 0.f;
    }
#pragma unroll
    for (int nc = 0; nc < 4; ++nc) {
#pragma unroll
      for (int reg = 0; reg < 4; ++reg) {
        const float p = exp2f(sc[nc][reg] - m[reg]);
        sc[nc][reg] = p;
        rs[reg] += p;
      }
    }
#pragma unroll
    for (int xm = 1; xm <= 8; xm <<= 1) {
#pragma unroll
      for (int reg = 0; reg < 4; ++reg)
        rs[reg] += __shfl_xor(rs[reg], xm);
    }
#pragma unroll
    for (int reg = 0; reg < 4; ++reg) l[reg] = l[reg] * fac[reg] + rs[reg];
#pragma unroll
    for (int nb = 0; nb < 4; ++nb) {
#pragma unroll
      for (int reg = 0; reg < 4; ++reg) o[nb][reg] *= fac[reg];
    }
    // ---- P -> LDS (bf16), re-fragment as PV A-operand ----
#pragma unroll
    for (int nc = 0; nc < 4; ++nc) {
#pragma unroll
      for (int reg = 0; reg < 4; ++reg)
        pt[g * 4 + reg][nc * 16 + r] = f2bf(sc[nc][reg]);
    }
    __syncthreads();
    const short8 a0 = *(const short8*)&pt[r][g * 8];
    const short8 a1 = *(const short8*)&pt[r][32 + g * 8];
#pragma unroll
    for (int nb = 0; nb < 4; ++nb) {
      const short* vp = Vb + (size_t)(nb * 16 + r) * SEQ + s0 + g * 8;
      short8 v0 = *(const short8*)(vp);
      short8 v1 = *(const short8*)(vp + 32);
      o[nb] = mfma16(a0, v0, o[nb]);
      o[nb] = mfma16(a1, v1, o[nb]);
    }
    __syncthreads();
  }
  // ---- epilogue: divide by l, store fp32 ----
#pragma unroll
  for (int reg = 0; reg < 4; ++reg) {
    const float inv = 1.f / l[reg];
    const size_t row = (size_t)b * SEQ + qbase + g * 4 + reg;
#pragma unroll
    for (int nb = 0; nb < 4; ++nb)
      out[row * 64 + nb * 16 + r] = o[nb][reg] * inv;
  }
}

extern "C" void kernel_launch(void* const* d_in, const int* in_sizes, int n_in,
                              void* d_out, int out_size, void* d_ws, size_t ws_size,
                              hipStream_t stream) {
  (void)in_sizes; (void)n_in; (void)out_size; (void)ws_size;
  const float* x  = (const float*)d_in[0];
  const float* wq = (const float*)d_in[1];
  const float* wk = (const float*)d_in[2];
  const float* wv = (const float*)d_in[3];
  float* out = (float*)d_out;

  short* ws  = (short*)d_ws;
  short* wbf = ws;               // 3 * 32768 bf16
  short* Qs  = ws + 98304;       // 4*4096*64
  short* Ks  = Qs + 1048576;
  short* Vt  = Ks + 1048576;     // transposed V: [4][64][4096]

  wconv_kernel<<<384, 256, 0, stream>>>(wq, wk, wv, wbf);
  proj_kernel<<<256, 256, 0, stream>>>(x, wbf, Qs, Ks, Vt);
  attn_kernel<<<1024, 64, 0, stream>>>(Qs, Ks, Vt, out);
}

// Round 5
// 169.588 us; speedup vs baseline: 1.2789x; 1.2789x over previous
//
#include <hip/hip_runtime.h>
#include <hip/hip_bf16.h>
#include <math.h>

typedef short short8 __attribute__((ext_vector_type(8)));
typedef __bf16 bf16x8 __attribute__((ext_vector_type(8)));
typedef float f32x4 __attribute__((ext_vector_type(4)));

#define SEQ 4096
#define QK_SCALE 0.18033688011112042f  /* (1/8) * log2(e) */

__device__ __forceinline__ short f2bf(float f) {
    __bf16 h = (__bf16)f;
    return __builtin_bit_cast(short, h);
}

__device__ __forceinline__ f32x4 mfma16(short8 a, short8 b, f32x4 c) {
    return __builtin_amdgcn_mfma_f32_16x16x32_bf16(
        __builtin_bit_cast(bf16x8, a), __builtin_bit_cast(bf16x8, b), c, 0, 0, 0);
}

// ---- kernel 1: W fp32 -> bf16, pre-fragmented for MFMA B-operand.
// Wf[mat][t=k0/32][nb][lane][j]  (lane=g*16+r)  = W_mat[nb*16+r][t*32+g*8+j]
// W_Q pre-scaled by 1/8*log2e. ----
__global__ __launch_bounds__(256) void wconv_kernel(
    const float* __restrict__ wq, const float* __restrict__ wk,
    const float* __restrict__ wv, short* __restrict__ out) {
  int i = blockIdx.x * 256 + threadIdx.x;
  const int j = i & 7, lane = (i >> 3) & 63, nb = (i >> 9) & 3;
  const int t = (i >> 11) & 15, mat = i >> 15;
  const int g = lane >> 4, r = lane & 15;
  const int src = (nb * 16 + r) * 512 + t * 32 + g * 8 + j;
  float v;
  if (mat == 0)      v = wq[src] * QK_SCALE;
  else if (mat == 1) v = wk[src];
  else               v = wv[src];
  out[i] = f2bf(v);
}

// ---- kernel 2: QKV projection. One matrix per block (mat = blk>>8).
// Q,K row-major bf16 [B*S][64]; V transposed Vt[b][k][s].
// 64 rows/block, 4 waves x 16 rows. Coalesced W loads (fragment order). ----
__global__ __launch_bounds__(256) void proj_kernel(
    const float* __restrict__ x, const short* __restrict__ wf,
    short* __restrict__ Qs, short* __restrict__ Ks, short* __restrict__ Vt) {
  __shared__ short stg[4][16][72];
  const int bb = blockIdx.x;
  const int mat = bb >> 8, rb = bb & 255;
  const int wave = threadIdx.x >> 6, lane = threadIdx.x & 63;
  const int g = lane >> 4, r = lane & 15;
  const int rbase = rb * 64 + wave * 16;
  const short* wbase = wf + (size_t)mat * 32768;

  f32x4 acc[4];
#pragma unroll
  for (int nb = 0; nb < 4; ++nb) acc[nb] = (f32x4)0.f;

  const float* xp = x + (size_t)(rbase + r) * 512;
#pragma unroll 4
  for (int k0 = 0; k0 < 512; k0 += 32) {
    const int kb = k0 + g * 8;
    f32x4 f0 = *(const f32x4*)(xp + kb);
    f32x4 f1 = *(const f32x4*)(xp + kb + 4);
    short8 a;
    a[0] = f2bf(f0[0]); a[1] = f2bf(f0[1]); a[2] = f2bf(f0[2]); a[3] = f2bf(f0[3]);
    a[4] = f2bf(f1[0]); a[5] = f2bf(f1[1]); a[6] = f2bf(f1[2]); a[7] = f2bf(f1[3]);
    const short* wp = wbase + ((size_t)(k0 >> 5) * 4 * 64 + lane) * 8;
#pragma unroll
    for (int nb = 0; nb < 4; ++nb) {
      short8 bq = *(const short8*)(wp + nb * 512);
      acc[nb] = mfma16(a, bq, acc[nb]);
    }
  }

  // stage C tile (wave-local LDS, no barrier needed)
#pragma unroll
  for (int nb = 0; nb < 4; ++nb) {
#pragma unroll
    for (int reg = 0; reg < 4; ++reg)
      stg[wave][g * 4 + reg][nb * 16 + r] = f2bf(acc[nb][reg]);
  }
  if (mat < 2) {
    short* dst = (mat == 0) ? Qs : Ks;
    const int orow = lane >> 2, ob = lane & 3;
    // 16 rows x 64 cols = 128 short8s; 64 lanes store 2 each (cols 0-31, 32-63)
    short8 v0 = *(const short8*)&stg[wave][orow][ob * 8];
    short8 v1 = *(const short8*)&stg[wave][orow][ob * 8 + 32];
    *(short8*)(dst + (size_t)(rbase + orow) * 64 + ob * 8) = v0;
    *(short8*)(dst + (size_t)(rbase + orow) * 64 + ob * 8 + 32) = v1;
  } else {
    const int b = rbase >> 12, sb = rbase & 4095;
    short* vrow = Vt + ((size_t)(b * 64 + lane)) * SEQ + sb;
    short8 v0, v1;
#pragma unroll
    for (int j = 0; j < 8; ++j) v0[j] = stg[wave][j][lane];
#pragma unroll
    for (int j = 0; j < 8; ++j) v1[j] = stg[wave][j + 8][lane];
    *(short8*)(vrow) = v0;
    *(short8*)(vrow + 8) = v1;
  }
}

// ---- kernel 3: flash attention, causal. 256 thr/block; 4 waves split the
// KV range of one 16-row q-tile, merge partials via LDS. ----
__global__ __launch_bounds__(256) void attn_kernel(
    const short* __restrict__ Qs, const short* __restrict__ Ks,
    const short* __restrict__ Vt, float* __restrict__ out) {
  __shared__ short pt[4][16][72];       // per-wave P staging
  __shared__ float pm[4][16], pl[4][16];
  __shared__ float po[4][16][64];
  const int blk = blockIdx.x;
  const int b = blk & 3;
  const int t = 255 - (blk >> 2);       // longest tiles dispatch first
  const int wave = threadIdx.x >> 6, lane = threadIdx.x & 63;
  const int g = lane >> 4, r = lane & 15;
  const int qbase = t * 16;
  const short* Qb = Qs + (size_t)b * (SEQ * 64);
  const short* Kb = Ks + (size_t)b * (SEQ * 64);
  const short* Vb = Vt + (size_t)b * (64 * SEQ);

  const short8 qf0 = *(const short8*)(Qb + (qbase + r) * 64 + g * 8);
  const short8 qf1 = *(const short8*)(Qb + (qbase + r) * 64 + 32 + g * 8);

  f32x4 o[4];
  float m[4], l[4];
#pragma unroll
  for (int i = 0; i < 4; ++i) { o[i] = (f32x4)0.f; m[i] = -1e30f; l[i] = 0.f; }

  const int smax = qbase + 15;
  for (int s0 = wave * 64; s0 <= smax; s0 += 256) {
    // ---- S = Q K^T (pre-scaled to log2 domain) ----
    f32x4 sc[4];
#pragma unroll
    for (int nc = 0; nc < 4; ++nc) {
      sc[nc] = (f32x4)0.f;
      const short* kp = Kb + (size_t)(s0 + nc * 16 + r) * 64 + g * 8;
      short8 kf0 = *(const short8*)(kp);
      short8 kf1 = *(const short8*)(kp + 32);
      sc[nc] = mfma16(qf0, kf0, sc[nc]);
      sc[nc] = mfma16(qf1, kf1, sc[nc]);
    }
    // ---- causal mask (only the diagonal block) ----
    if (s0 + 63 > qbase) {
#pragma unroll
      for (int nc = 0; nc < 4; ++nc) {
        const int s = s0 + nc * 16 + r;
#pragma unroll
        for (int reg = 0; reg < 4; ++reg) {
          const int q = qbase + g * 4 + reg;
          if (s > q) sc[nc][reg] = -1e30f;
        }
      }
    }
    // ---- online softmax (base-2) ----
    float mb[4];
#pragma unroll
    for (int reg = 0; reg < 4; ++reg)
      mb[reg] = fmaxf(fmaxf(sc[0][reg], sc[1][reg]), fmaxf(sc[2][reg], sc[3][reg]));
#pragma unroll
    for (int xm = 1; xm <= 8; xm <<= 1) {
#pragma unroll
      for (int reg = 0; reg < 4; ++reg)
        mb[reg] = fmaxf(mb[reg], __shfl_xor(mb[reg], xm));
    }
    float fac[4], rs[4];
#pragma unroll
    for (int reg = 0; reg < 4; ++reg) {
      const float mn = fmaxf(m[reg], mb[reg]);
      fac[reg] = exp2f(m[reg] - mn);
      m[reg] = mn;
      rs[reg] = 0.f;
    }
#pragma unroll
    for (int nc = 0; nc < 4; ++nc) {
#pragma unroll
      for (int reg = 0; reg < 4; ++reg) {
        const float p = exp2f(sc[nc][reg] - m[reg]);
        sc[nc][reg] = p;
        rs[reg] += p;
      }
    }
#pragma unroll
    for (int xm = 1; xm <= 8; xm <<= 1) {
#pragma unroll
      for (int reg = 0; reg < 4; ++reg)
        rs[reg] += __shfl_xor(rs[reg], xm);
    }
#pragma unroll
    for (int reg = 0; reg < 4; ++reg) l[reg] = l[reg] * fac[reg] + rs[reg];
#pragma unroll
    for (int nb = 0; nb < 4; ++nb) {
#pragma unroll
      for (int reg = 0; reg < 4; ++reg) o[nb][reg] *= fac[reg];
    }
    // ---- P -> wave-local LDS (bf16), re-fragment as PV A-operand ----
#pragma unroll
    for (int nc = 0; nc < 4; ++nc) {
#pragma unroll
      for (int reg = 0; reg < 4; ++reg)
        pt[wave][g * 4 + reg][nc * 16 + r] = f2bf(sc[nc][reg]);
    }
    const short8 a0 = *(const short8*)&pt[wave][r][g * 8];
    const short8 a1 = *(const short8*)&pt[wave][r][32 + g * 8];
#pragma unroll
    for (int nb = 0; nb < 4; ++nb) {
      const short* vp = Vb + (size_t)(nb * 16 + r) * SEQ + s0 + g * 8;
      short8 v0 = *(const short8*)(vp);
      short8 v1 = *(const short8*)(vp + 32);
      o[nb] = mfma16(a0, v0, o[nb]);
      o[nb] = mfma16(a1, v1, o[nb]);
    }
  }
  // ---- write per-wave partials ----
#pragma unroll
  for (int nb = 0; nb < 4; ++nb) {
#pragma unroll
    for (int reg = 0; reg < 4; ++reg)
      po[wave][g * 4 + reg][nb * 16 + r] = o[nb][reg];
  }
  if (r == 0) {
#pragma unroll
    for (int reg = 0; reg < 4; ++reg) {
      pm[wave][g * 4 + reg] = m[reg];
      pl[wave][g * 4 + reg] = l[reg];
    }
  }
  __syncthreads();
  // ---- merge 4 partials: thread -> (row, col) ----
  {
    const int tid = threadIdx.x;
    const int row = tid >> 4, cb = tid & 15;
    float M = -1e30f;
#pragma unroll
    for (int w = 0; w < 4; ++w) M = fmaxf(M, pm[w][row]);
    float scw[4];
    float L = 0.f;
#pragma unroll
    for (int w = 0; w < 4; ++w) {
      scw[w] = exp2f(pm[w][row] - M);
      L += pl[w][row] * scw[w];
    }
    const float inv = 1.f / L;
    const size_t obase = ((size_t)b * SEQ + qbase + row) * 64;
#pragma unroll
    for (int j = 0; j < 4; ++j) {
      const int c = j * 16 + cb;
      float acc = 0.f;
#pragma unroll
      for (int w = 0; w < 4; ++w) acc += po[w][row][c] * scw[w];
      out[obase + c] = acc * inv;
    }
  }
}

extern "C" void kernel_launch(void* const* d_in, const int* in_sizes, int n_in,
                              void* d_out, int out_size, void* d_ws, size_t ws_size,
                              hipStream_t stream) {
  (void)in_sizes; (void)n_in; (void)out_size; (void)ws_size;
  const float* x  = (const float*)d_in[0];
  const float* wq = (const float*)d_in[1];
  const float* wk = (const float*)d_in[2];
  const float* wv = (const float*)d_in[3];
  float* out = (float*)d_out;

  short* ws  = (short*)d_ws;
  short* wbf = ws;               // 3 * 32768 bf16 (fragment-ordered)
  short* Qs  = ws + 98304;       // 4*4096*64
  short* Ks  = Qs + 1048576;
  short* Vt  = Ks + 1048576;     // transposed V: [4][64][4096]

  wconv_kernel<<<384, 256, 0, stream>>>(wq, wk, wv, wbf);
  proj_kernel<<<768, 256, 0, stream>>>(x, wbf, Qs, Ks, Vt);
  attn_kernel<<<1024, 256, 0, stream>>>(Qs, Ks, Vt, out);
}

// Round 6
// 140.772 us; speedup vs baseline: 1.5406x; 1.2047x over previous
//
#include <hip/hip_runtime.h>
#include <hip/hip_bf16.h>
#include <math.h>

typedef short short4v __attribute__((ext_vector_type(4)));
typedef short short8 __attribute__((ext_vector_type(8)));
typedef __bf16 bf16x8 __attribute__((ext_vector_type(8)));
typedef float f32x4 __attribute__((ext_vector_type(4)));

#define SEQ 4096
#define QK_SCALE 0.18033688011112042f  /* (1/8) * log2(e) */

__device__ __forceinline__ short f2bf(float f) {
    __bf16 h = (__bf16)f;
    return __builtin_bit_cast(short, h);
}

__device__ __forceinline__ float exp2a(float x) {  // raw v_exp_f32 (2^x), 1 instr
    float r;
    asm("v_exp_f32 %0, %1" : "=v"(r) : "v"(x));
    return r;
}

__device__ __forceinline__ f32x4 mfma16(short8 a, short8 b, f32x4 c) {
    return __builtin_amdgcn_mfma_f32_16x16x32_bf16(
        __builtin_bit_cast(bf16x8, a), __builtin_bit_cast(bf16x8, b), c, 0, 0, 0);
}

// ---- kernel 1: W fp32 -> bf16, pre-fragmented for MFMA B-operand. ----
__global__ __launch_bounds__(256) void wconv_kernel(
    const float* __restrict__ wq, const float* __restrict__ wk,
    const float* __restrict__ wv, short* __restrict__ out) {
  int i = blockIdx.x * 256 + threadIdx.x;
  const int j = i & 7, lane = (i >> 3) & 63, nb = (i >> 9) & 3;
  const int t = (i >> 11) & 15, mat = i >> 15;
  const int g = lane >> 4, r = lane & 15;
  const int src = (nb * 16 + r) * 512 + t * 32 + g * 8 + j;
  float v;
  if (mat == 0)      v = wq[src] * QK_SCALE;
  else if (mat == 1) v = wk[src];
  else               v = wv[src];
  out[i] = f2bf(v);
}

// ---- kernel 2: QKV projection (unchanged from round 5; passed). ----
__global__ __launch_bounds__(256) void proj_kernel(
    const float* __restrict__ x, const short* __restrict__ wf,
    short* __restrict__ Qs, short* __restrict__ Ks, short* __restrict__ Vt) {
  __shared__ short stg[4][16][72];
  const int bb = blockIdx.x;
  const int mat = bb >> 8, rb = bb & 255;
  const int wave = threadIdx.x >> 6, lane = threadIdx.x & 63;
  const int g = lane >> 4, r = lane & 15;
  const int rbase = rb * 64 + wave * 16;
  const short* wbase = wf + (size_t)mat * 32768;

  f32x4 acc[4];
#pragma unroll
  for (int nb = 0; nb < 4; ++nb) acc[nb] = (f32x4)0.f;

  const float* xp = x + (size_t)(rbase + r) * 512;
#pragma unroll 4
  for (int k0 = 0; k0 < 512; k0 += 32) {
    const int kb = k0 + g * 8;
    f32x4 f0 = *(const f32x4*)(xp + kb);
    f32x4 f1 = *(const f32x4*)(xp + kb + 4);
    short8 a;
    a[0] = f2bf(f0[0]); a[1] = f2bf(f0[1]); a[2] = f2bf(f0[2]); a[3] = f2bf(f0[3]);
    a[4] = f2bf(f1[0]); a[5] = f2bf(f1[1]); a[6] = f2bf(f1[2]); a[7] = f2bf(f1[3]);
    const short* wp = wbase + ((size_t)(k0 >> 5) * 4 * 64 + lane) * 8;
#pragma unroll
    for (int nb = 0; nb < 4; ++nb) {
      short8 bq = *(const short8*)(wp + nb * 512);
      acc[nb] = mfma16(a, bq, acc[nb]);
    }
  }

#pragma unroll
  for (int nb = 0; nb < 4; ++nb) {
#pragma unroll
    for (int reg = 0; reg < 4; ++reg)
      stg[wave][g * 4 + reg][nb * 16 + r] = f2bf(acc[nb][reg]);
  }
  if (mat < 2) {
    short* dst = (mat == 0) ? Qs : Ks;
    const int orow = lane >> 2, ob = lane & 3;
    short8 v0 = *(const short8*)&stg[wave][orow][ob * 8];
    short8 v1 = *(const short8*)&stg[wave][orow][ob * 8 + 32];
    *(short8*)(dst + (size_t)(rbase + orow) * 64 + ob * 8) = v0;
    *(short8*)(dst + (size_t)(rbase + orow) * 64 + ob * 8 + 32) = v1;
  } else {
    const int b = rbase >> 12, sb = rbase & 4095;
    short* vrow = Vt + ((size_t)(b * 64 + lane)) * SEQ + sb;
    short8 v0, v1;
#pragma unroll
    for (int j = 0; j < 8; ++j) v0[j] = stg[wave][j][lane];
#pragma unroll
    for (int j = 0; j < 8; ++j) v1[j] = stg[wave][j + 8][lane];
    *(short8*)(vrow) = v0;
    *(short8*)(vrow + 8) = v1;
  }
}

// ---- kernel 3: flash attention, causal, swapped-operand MFMA.
// 512 blocks: 32 q-rows/block (2 rowblocks of 16), 4 waves KV-split.
// Swapped QK (mfma(K,Q)) => lane owns one q-row (q = lane&15): softmax is
// lane-local (2 shfl). P^T staged [q][s] with ds_write_b64; PV = V^T * P^T. ----
__global__ __launch_bounds__(256) void attn_kernel(
    const short* __restrict__ Qs, const short* __restrict__ Ks,
    const short* __restrict__ Vt, float* __restrict__ out) {
  __shared__ __align__(16) short ptq[4][2][16][80];  // [wave][rb][q][s] stride 80
  __shared__ __align__(16) float po[4][32][68];
  __shared__ float pm[4][32], pl[4][32];
  const int blk = blockIdx.x;
  const int b = blk & 3;
  const int t = 127 - (blk >> 2);       // longest tiles dispatch first
  const int wave = threadIdx.x >> 6, lane = threadIdx.x & 63;
  const int g = lane >> 4, r = lane & 15;
  const int qbase = t * 32;
  const short* Qb = Qs + (size_t)b * (SEQ * 64);
  const short* Kb = Ks + (size_t)b * (SEQ * 64);
  const short* Vb = Vt + (size_t)b * (64 * SEQ);

  // Q fragments (B-operand: Q[q=r][k]) for both rowblocks
  short8 qf[2][2];
#pragma unroll
  for (int rb = 0; rb < 2; ++rb) {
    const int qoff = (qbase + rb * 16 + r) * 64 + g * 8;
    qf[rb][0] = *(const short8*)(Qb + qoff);
    qf[rb][1] = *(const short8*)(Qb + qoff + 32);
  }

  f32x4 o[2][4];
  float m[2] = {-1e30f, -1e30f}, l[2] = {0.f, 0.f};
#pragma unroll
  for (int rb = 0; rb < 2; ++rb)
#pragma unroll
    for (int nb = 0; nb < 4; ++nb) o[rb][nb] = (f32x4)0.f;

  for (int s0 = wave * 64; s0 <= qbase + 31; s0 += 256) {
    // K fragments (A-operand: K[s][k]), shared by both rowblocks
    short8 kf0[4], kf1[4];
#pragma unroll
    for (int nc = 0; nc < 4; ++nc) {
      const int koff = (s0 + nc * 16 + r) * 64 + g * 8;
      kf0[nc] = *(const short8*)(Kb + koff);
      kf1[nc] = *(const short8*)(Kb + koff + 32);
    }
    // V fragments hoisted (A-operand: Vt[d][s]), shared
    short8 vv0[4], vv1[4];
#pragma unroll
    for (int nb = 0; nb < 4; ++nb) {
      const int voff = (nb * 16 + r) * SEQ + s0 + g * 8;
      vv0[nb] = *(const short8*)(Vb + voff);
      vv1[nb] = *(const short8*)(Vb + voff + 32);
    }

#pragma unroll
    for (int rb = 0; rb < 2; ++rb) {
      // ---- S^T tiles: D[row=s][col=q], lane: q=r, s=s0+nc*16+g*4+reg ----
      f32x4 sc[4];
#pragma unroll
      for (int nc = 0; nc < 4; ++nc) {
        sc[nc] = (f32x4)0.f;
        sc[nc] = mfma16(kf0[nc], qf[rb][0], sc[nc]);
        sc[nc] = mfma16(kf1[nc], qf[rb][1], sc[nc]);
      }
      const int q = qbase + rb * 16 + r;
      // ---- causal mask (diagonal tiles only) ----
      if (s0 + 63 > q) {
#pragma unroll
        for (int nc = 0; nc < 4; ++nc) {
          const int sbase = s0 + nc * 16 + g * 4;
#pragma unroll
          for (int reg = 0; reg < 4; ++reg)
            if (sbase + reg > q) sc[nc][reg] = -1e30f;
        }
      }
      // ---- online softmax: lane-local row (16 vals) + 2 shfl ----
      float mx = fmaxf(fmaxf(sc[0][0], sc[0][1]), fmaxf(sc[0][2], sc[0][3]));
#pragma unroll
      for (int nc = 1; nc < 4; ++nc)
        mx = fmaxf(mx, fmaxf(fmaxf(sc[nc][0], sc[nc][1]), fmaxf(sc[nc][2], sc[nc][3])));
      mx = fmaxf(mx, __shfl_xor(mx, 16));
      mx = fmaxf(mx, __shfl_xor(mx, 32));
      const float mn = fmaxf(m[rb], mx);
      const float fac = exp2a(m[rb] - mn);
      m[rb] = mn;
      float rs = 0.f;
#pragma unroll
      for (int nc = 0; nc < 4; ++nc) {
#pragma unroll
        for (int reg = 0; reg < 4; ++reg) {
          const float p = exp2a(sc[nc][reg] - mn);
          sc[nc][reg] = p;
          rs += p;
        }
      }
      rs += __shfl_xor(rs, 16);
      rs += __shfl_xor(rs, 32);
      l[rb] = l[rb] * fac + rs;
#pragma unroll
      for (int nb = 0; nb < 4; ++nb) o[rb][nb] *= fac;
      // ---- P^T -> LDS [q][s]: 4x ds_write_b64 (s-consecutive) ----
#pragma unroll
      for (int nc = 0; nc < 4; ++nc) {
        short4v p4;
        p4[0] = f2bf(sc[nc][0]); p4[1] = f2bf(sc[nc][1]);
        p4[2] = f2bf(sc[nc][2]); p4[3] = f2bf(sc[nc][3]);
        *(short4v*)&ptq[wave][rb][r][nc * 16 + g * 4] = p4;
      }
      // ---- PV: O^T[d][q] += V^T[d][s] * P^T[s][q] ----
      const short8 pa0 = *(const short8*)&ptq[wave][rb][r][g * 8];
      const short8 pa1 = *(const short8*)&ptq[wave][rb][r][32 + g * 8];
#pragma unroll
      for (int nb = 0; nb < 4; ++nb) {
        o[rb][nb] = mfma16(vv0[nb], pa0, o[rb][nb]);
        o[rb][nb] = mfma16(vv1[nb], pa1, o[rb][nb]);
      }
    }
  }

  // ---- per-wave partials: po[wave][qrow][d] (lane holds d=nb*16+g*4+reg, q=r) ----
#pragma unroll
  for (int rb = 0; rb < 2; ++rb) {
#pragma unroll
    for (int nb = 0; nb < 4; ++nb)
      *(f32x4*)&po[wave][rb * 16 + r][nb * 16 + g * 4] = o[rb][nb];
    if (g == 0) {
      pm[wave][rb * 16 + r] = m[rb];
      pl[wave][rb * 16 + r] = l[rb];
    }
  }
  __syncthreads();
  // ---- merge 4 wave-partials; thread -> (row, 8 cols) ----
  {
    const int tid = threadIdx.x;
    const int row = tid >> 3, cb = (tid & 7) * 8;
    float M = fmaxf(fmaxf(pm[0][row], pm[1][row]), fmaxf(pm[2][row], pm[3][row]));
    float scw[4], L = 0.f;
#pragma unroll
    for (int w = 0; w < 4; ++w) {
      scw[w] = exp2a(pm[w][row] - M);
      L += pl[w][row] * scw[w];
    }
    const float inv = 1.f / L;
    f32x4 acc0 = (f32x4)0.f, acc1 = (f32x4)0.f;
#pragma unroll
    for (int w = 0; w < 4; ++w) {
      const f32x4 a = *(const f32x4*)&po[w][row][cb];
      const f32x4 c = *(const f32x4*)&po[w][row][cb + 4];
      acc0 += a * scw[w];
      acc1 += c * scw[w];
    }
    acc0 *= inv; acc1 *= inv;
    float* op = out + ((size_t)b * SEQ + qbase + row) * 64 + cb;
    *(f32x4*)op = acc0;
    *(f32x4*)(op + 4) = acc1;
  }
}

extern "C" void kernel_launch(void* const* d_in, const int* in_sizes, int n_in,
                              void* d_out, int out_size, void* d_ws, size_t ws_size,
                              hipStream_t stream) {
  (void)in_sizes; (void)n_in; (void)out_size; (void)ws_size;
  const float* x  = (const float*)d_in[0];
  const float* wq = (const float*)d_in[1];
  const float* wk = (const float*)d_in[2];
  const float* wv = (const float*)d_in[3];
  float* out = (float*)d_out;

  short* ws  = (short*)d_ws;
  short* wbf = ws;               // 3 * 32768 bf16 (fragment-ordered)
  short* Qs  = ws + 98304;       // 4*4096*64
  short* Ks  = Qs + 1048576;
  short* Vt  = Ks + 1048576;     // transposed V: [4][64][4096]

  wconv_kernel<<<384, 256, 0, stream>>>(wq, wk, wv, wbf);
  proj_kernel<<<768, 256, 0, stream>>>(x, wbf, Qs, Ks, Vt);
  attn_kernel<<<512, 256, 0, stream>>>(Qs, Ks, Vt, out);
}